// Round 2
// baseline (524.239 us; speedup 1.0000x reference)
//
#include <hip/hip_runtime.h>
#include <hip/hip_bf16.h>
#include <math.h>

// Problem constants (Qwen3 MoE experts)
#define E_N 32
#define H_N 1024
#define I_N 768
#define T_N 2048
#define K_N 8
#define MT  128                        // M-tile: slots per expert tile
#define NPAIRS (T_N * K_N)             // 16384 (t,k) pairs
#define MAX_SLOTS (NPAIRS + E_N * MT)  // 20480 padded slots (worst case)
#define MAX_TILES (NPAIRS / MT + E_N)  // 160 tiles (worst case)

typedef __attribute__((ext_vector_type(8))) short bf16x8;  // 8 bf16 = 4 VGPRs
typedef __attribute__((ext_vector_type(4))) short bf16x4;
typedef __attribute__((ext_vector_type(8))) float f32x8;
typedef __attribute__((ext_vector_type(4))) float f32x4;

// pack two fp32 -> two bf16 (round-half-up: ~0.5 ulp, 3 VALU)
__device__ __forceinline__ unsigned pk2(float a, float b) {
    unsigned ua = __float_as_uint(a) + 0x8000u;
    unsigned ub = __float_as_uint(b) + 0x8000u;
    return (ua >> 16) | (ub & 0xffff0000u);
}
__device__ __forceinline__ bf16x8 cvt8(f32x8 v) {
    union { unsigned u[4]; bf16x8 h; } r;
    r.u[0] = pk2(v[0], v[1]); r.u[1] = pk2(v[2], v[3]);
    r.u[2] = pk2(v[4], v[5]); r.u[3] = pk2(v[6], v[7]);
    return r.h;
}
__device__ __forceinline__ float bf2f(short s) {
    return __uint_as_float(((unsigned)(unsigned short)s) << 16);
}

// async global->LDS DMA, 16B per lane. LDS dest = wave-uniform base + lane*16
// (m104/m108). Global src is per-lane.
__device__ __forceinline__ void gload16(const void* g, void* l) {
    __builtin_amdgcn_global_load_lds(
        (const __attribute__((address_space(1))) unsigned int*)g,
        (__attribute__((address_space(3))) unsigned int*)l, 16, 0, 0);
}

// ---------------------------------------------------------------------------
// Kernel 1: routing. Bucket (t,k) pairs by expert, pad to MT=128, build tile
// table. slot_token pre-initialized to -1 via hipMemsetAsync(0xFF).
// ---------------------------------------------------------------------------
__global__ void route_kernel(const int* __restrict__ sel,
                             int* __restrict__ slot_token,
                             int* __restrict__ pair_slot,
                             int* __restrict__ tile_expert,
                             int* __restrict__ tile_row0,
                             int* __restrict__ n_tiles_out) {
    __shared__ int cnt[E_N], off[E_N], cur[E_N];
    int tid = threadIdx.x;
    if (tid < E_N) cnt[tid] = 0;
    __syncthreads();
    for (int p = tid; p < NPAIRS; p += blockDim.x)
        atomicAdd(&cnt[sel[p]], 1);
    __syncthreads();
    if (tid == 0) {
        int acc = 0, tt = 0;
        for (int e = 0; e < E_N; ++e) {
            off[e] = acc;
            cur[e] = 0;
            int nt = (cnt[e] + MT - 1) / MT;
            for (int i = 0; i < nt; ++i) {
                tile_expert[tt] = e;
                tile_row0[tt] = acc + i * MT;
                ++tt;
            }
            acc += nt * MT;
        }
        *n_tiles_out = tt;
    }
    __syncthreads();
    for (int p = tid; p < NPAIRS; p += blockDim.x) {
        int e = sel[p];
        int slot = off[e] + atomicAdd(&cur[e], 1);
        slot_token[slot] = p / K_N;  // token index
        pair_slot[p] = slot;
    }
}

// ---------------------------------------------------------------------------
// Kernel 2: gather tokens -> contiguous bf16 x_buf[slot][H]; pad slots = 0.
// ---------------------------------------------------------------------------
__global__ __launch_bounds__(256) void gather_kernel(
    const float* __restrict__ hs,
    const int* __restrict__ slot_token,
    short* __restrict__ x_buf) {
    int idx = blockIdx.x * 256 + threadIdx.x;   // one thread per 4 elems
    int slot = idx >> 8;                        // H_N/4 = 256 threads/slot
    int pos = (idx & 255) * 4;
    int tok = slot_token[slot];
    union { unsigned u[2]; bf16x4 s; } o;
    if (tok >= 0) {
        f32x4 v = *(const f32x4*)(hs + (size_t)tok * H_N + pos);
        o.u[0] = pk2(v[0], v[1]);
        o.u[1] = pk2(v[2], v[3]);
    } else {
        o.u[0] = 0; o.u[1] = 0;
    }
    *(bf16x4*)(x_buf + (size_t)slot * H_N + pos) = o.s;
}

// ---------------------------------------------------------------------------
// Kernel 2b: weight convert fp32 -> bf16, grid-stride streaming.
// ---------------------------------------------------------------------------
__global__ __launch_bounds__(256) void cvt_kernel(
    const float* __restrict__ src, short* __restrict__ dst, int n8) {
    int i = blockIdx.x * 256 + threadIdx.x;
    int stride = gridDim.x * 256;
    for (; i < n8; i += stride) {
        f32x8 v = *(const f32x8*)(src + (size_t)i * 8);
        *(bf16x8*)(dst + (size_t)i * 8) = cvt8(v);
    }
}

// ---------------------------------------------------------------------------
// Kernel 3: gate/up GEMM + SwiGLU, m97-faithful structure:
// 128x128 tile, 4 waves (2x2), wave 64x64 for BOTH G and U (shared A), BK=32.
// A/G/U all bf16 in global; staged via global_load_lds width=16 into linear
// [128][32]-short LDS (single-buffered, 2 barriers/iter). No staging VGPRs,
// no cvt in the loop.
// Staging decomposition: per 8KB array = 8 chunks of 16 rows x 64B; wave w
// stages chunks {2w, 2w+1}; within a call lane l covers row rb+(l>>2),
// 16B col-chunk (l&3)  == HW's base+lane*16 linear fill.
// ---------------------------------------------------------------------------
__global__ __launch_bounds__(256, 2) void gateup_kernel(
    const short* __restrict__ x_buf,
    const short* __restrict__ wg,     // bf16 [E][I][H]
    const short* __restrict__ wu,     // bf16 [E][I][H]
    const int* __restrict__ tile_expert,
    const int* __restrict__ tile_row0,
    const int* __restrict__ n_tiles,
    __hip_bfloat16* __restrict__ h_buf) {
    // swizzle: 960 blocks, 120 consecutive work items per XCD
    int id = blockIdx.x;
    int W = (id & 7) * 120 + (id >> 3);
    int tile = W % MAX_TILES;       // tiles consecutive within an XCD's range
    int ycol = W / MAX_TILES;       // 0..5
    if (tile >= *n_tiles) return;
    __shared__ short sA[128 * 32];
    __shared__ short sG[128 * 32];
    __shared__ short sU[128 * 32];
    int e = tile_expert[tile];
    int row0 = tile_row0[tile];
    int col0 = ycol * 128;  // in I
    int tid = threadIdx.x;
    int wave = tid >> 6, lane = tid & 63, quad = lane >> 4, r16 = lane & 15;
    int m0w = (wave >> 1) * 64, n0w = (wave & 1) * 64;
    int srow = lane >> 2;         // 0..15 within staging chunk
    int scb = (lane & 3) * 8;     // 16B col-chunk (shorts)

    f32x4 accG[4][4], accU[4][4];
#pragma unroll
    for (int i = 0; i < 4; ++i)
#pragma unroll
        for (int j = 0; j < 4; ++j) {
            accG[i][j] = (f32x4){0.f, 0.f, 0.f, 0.f};
            accU[i][j] = (f32x4){0.f, 0.f, 0.f, 0.f};
        }

    const short* Ag = x_buf + (size_t)row0 * H_N;
    const short* Gg = wg + ((size_t)e * I_N + col0) * H_N;
    const short* Ug = wu + ((size_t)e * I_N + col0) * H_N;

#pragma unroll 1
    for (int k0 = 0; k0 < H_N; k0 += 32) {
        __syncthreads();  // prior iter's frag reads done before DMA overwrite
#pragma unroll
        for (int c = 0; c < 2; ++c) {
            int rb = (wave * 2 + c) * 16;          // chunk base row
            size_t goff = (size_t)(rb + srow) * H_N + k0 + scb;
            gload16(Ag + goff, &sA[rb * 32]);
            gload16(Gg + goff, &sG[rb * 32]);
            gload16(Ug + goff, &sU[rb * 32]);
        }
        __syncthreads();  // vmcnt(0)+lgkm drain: staged data visible
        bf16x8 af[4], bg[4], bu[4];
#pragma unroll
        for (int mi = 0; mi < 4; ++mi)
            af[mi] = *(const bf16x8*)&sA[(m0w + mi * 16 + r16) * 32 + quad * 8];
#pragma unroll
        for (int ni = 0; ni < 4; ++ni) {
            bg[ni] = *(const bf16x8*)&sG[(n0w + ni * 16 + r16) * 32 + quad * 8];
            bu[ni] = *(const bf16x8*)&sU[(n0w + ni * 16 + r16) * 32 + quad * 8];
        }
        __builtin_amdgcn_s_setprio(1);
#pragma unroll
        for (int mi = 0; mi < 4; ++mi)
#pragma unroll
            for (int ni = 0; ni < 4; ++ni) {
                accG[mi][ni] = __builtin_amdgcn_mfma_f32_16x16x32_bf16(af[mi], bg[ni], accG[mi][ni], 0, 0, 0);
                accU[mi][ni] = __builtin_amdgcn_mfma_f32_16x16x32_bf16(af[mi], bu[ni], accU[mi][ni], 0, 0, 0);
            }
        __builtin_amdgcn_s_setprio(0);
    }
    // C/D layout: col(n)=lane&15, row(m)=quad*4+reg  [verified round 2]
#pragma unroll
    for (int mi = 0; mi < 4; ++mi)
#pragma unroll
        for (int ni = 0; ni < 4; ++ni)
#pragma unroll
            for (int r = 0; r < 4; ++r) {
                int m = m0w + mi * 16 + quad * 4 + r;
                int n = col0 + n0w + ni * 16 + r16;
                float g = accG[mi][ni][r], u = accU[mi][ni][r];
                float hval = g * u / (1.0f + __expf(-g));
                h_buf[(size_t)(row0 + m) * I_N + n] = __float2bfloat16(hval);
            }
}

// ---------------------------------------------------------------------------
// Kernel 4: down GEMM, same m97 structure. A = h_buf bf16, B = wd bf16
// [E][H][I]. 16 MFMA/wave-iter, acc only 64 regs -> 3 blocks/CU.
// ---------------------------------------------------------------------------
__global__ __launch_bounds__(256, 3) void down_kernel(
    const __hip_bfloat16* __restrict__ h_buf,
    const short* __restrict__ wd,     // bf16 [E][H][I]
    const int* __restrict__ tile_expert,
    const int* __restrict__ tile_row0,
    const int* __restrict__ n_tiles,
    short* __restrict__ d_buf) {
    // swizzle: 1280 blocks, 160 consecutive work items per XCD
    int id = blockIdx.x;
    int W = (id & 7) * 160 + (id >> 3);
    int tile = W % MAX_TILES;
    int ycol = W / MAX_TILES;       // 0..7
    if (tile >= *n_tiles) return;
    __shared__ short sA[128 * 32];
    __shared__ short sB[128 * 32];
    int e = tile_expert[tile];
    int row0 = tile_row0[tile];
    int col0 = ycol * 128;  // in H
    int tid = threadIdx.x;
    int wave = tid >> 6, lane = tid & 63, quad = lane >> 4, r16 = lane & 15;
    int m0w = (wave >> 1) * 64, n0w = (wave & 1) * 64;
    int srow = lane >> 2;
    int scb = (lane & 3) * 8;

    f32x4 acc[4][4];
#pragma unroll
    for (int i = 0; i < 4; ++i)
#pragma unroll
        for (int j = 0; j < 4; ++j) acc[i][j] = (f32x4){0.f, 0.f, 0.f, 0.f};

    const short* Ag = (const short*)h_buf + (size_t)row0 * I_N;
    const short* Bg = wd + ((size_t)e * H_N + col0) * I_N;

#pragma unroll 1
    for (int k0 = 0; k0 < I_N; k0 += 32) {
        __syncthreads();
#pragma unroll
        for (int c = 0; c < 2; ++c) {
            int rb = (wave * 2 + c) * 16;
            size_t goff = (size_t)(rb + srow) * I_N + k0 + scb;
            gload16(Ag + goff, &sA[rb * 32]);
            gload16(Bg + goff, &sB[rb * 32]);
        }
        __syncthreads();
        bf16x8 af[4], bf[4];
#pragma unroll
        for (int mi = 0; mi < 4; ++mi)
            af[mi] = *(const bf16x8*)&sA[(m0w + mi * 16 + r16) * 32 + quad * 8];
#pragma unroll
        for (int ni = 0; ni < 4; ++ni)
            bf[ni] = *(const bf16x8*)&sB[(n0w + ni * 16 + r16) * 32 + quad * 8];
        __builtin_amdgcn_s_setprio(1);
#pragma unroll
        for (int mi = 0; mi < 4; ++mi)
#pragma unroll
            for (int ni = 0; ni < 4; ++ni)
                acc[mi][ni] = __builtin_amdgcn_mfma_f32_16x16x32_bf16(af[mi], bf[ni], acc[mi][ni], 0, 0, 0);
        __builtin_amdgcn_s_setprio(0);
    }
#pragma unroll
    for (int mi = 0; mi < 4; ++mi)
#pragma unroll
        for (int ni = 0; ni < 4; ++ni)
#pragma unroll
            for (int r = 0; r < 4; ++r) {
                int m = m0w + mi * 16 + quad * 4 + r;
                int n = col0 + n0w + ni * 16 + r16;
                unsigned u = __float_as_uint(acc[mi][ni][r]) + 0x8000u;
                d_buf[(size_t)(row0 + m) * H_N + n] = (short)(u >> 16);
            }
}

// ---------------------------------------------------------------------------
// Kernel 5: combine. out[t,h] = sum_k rw[t,k] * d_buf[pair_slot[t,k], h].
// ---------------------------------------------------------------------------
__global__ __launch_bounds__(256) void combine_kernel(
    const short* __restrict__ d_buf,
    const int* __restrict__ pair_slot,
    const float* __restrict__ rw,
    float* __restrict__ out) {
    int idx = blockIdx.x * blockDim.x + threadIdx.x;
    int t = idx >> 10;          // H_N = 1024
    int h = idx & (H_N - 1);
    float acc = 0.f;
#pragma unroll
    for (int k = 0; k < K_N; ++k) {
        int slot = pair_slot[t * K_N + k];
        float w = rw[t * K_N + k];
        acc += w * bf2f(d_buf[(size_t)slot * H_N + h]);
    }
    out[idx] = acc;
}

// ---------------------------------------------------------------------------
extern "C" void kernel_launch(void* const* d_in, const int* in_sizes, int n_in,
                              void* d_out, int out_size, void* d_ws, size_t ws_size,
                              hipStream_t stream) {
    const float* hs   = (const float*)d_in[0];
    const float* rw   = (const float*)d_in[1];
    const int*   sel  = (const int*)d_in[2];
    const float* gate = (const float*)d_in[3];
    const float* up   = (const float*)d_in[4];
    const float* down = (const float*)d_in[5];
    float* out = (float*)d_out;

    // Workspace carve-up (256B-aligned), ~174 MB peak:
    //   misc tables | x_buf 41.9MB (reused as d_buf) | h_buf 31.5MB |
    //   w_buf 100.7MB (wg|wu during gateup; wd reuses wg's half for down)
    const size_t WN = (size_t)E_N * I_N * H_N;  // elems per weight tensor
    char* ws = (char*)d_ws;
    int* slot_token  = (int*)ws;  ws += ((size_t)MAX_SLOTS * 4 + 255) / 256 * 256;
    int* pair_slot   = (int*)ws;  ws += ((size_t)NPAIRS * 4 + 255) / 256 * 256;
    int* tile_expert = (int*)ws;  ws += ((size_t)MAX_TILES * 4 + 255) / 256 * 256;
    int* tile_row0   = (int*)ws;  ws += ((size_t)MAX_TILES * 4 + 255) / 256 * 256;
    int* n_tiles     = (int*)ws;  ws += 256;
    short* x_buf = (short*)ws;    ws += ((size_t)MAX_SLOTS * H_N * 2 + 255) / 256 * 256;
    __hip_bfloat16* h_buf = (__hip_bfloat16*)ws;
    ws += ((size_t)MAX_SLOTS * I_N * 2 + 255) / 256 * 256;
    short* wg = (short*)ws;       // E*I*H bf16
    short* wu = wg + WN;          // E*I*H bf16
    short* wd = wg;               // reuses wg region after gateup
    short* d_buf = x_buf;         // reuses x region after gateup

    hipMemsetAsync(slot_token, 0xFF, (size_t)MAX_SLOTS * 4, stream);
    route_kernel<<<1, 256, 0, stream>>>(sel, slot_token, pair_slot,
                                        tile_expert, tile_row0, n_tiles);
    gather_kernel<<<(MAX_SLOTS * H_N / 4) / 256, 256, 0, stream>>>(hs, slot_token, x_buf);

    const int N8 = (int)(WN / 8);
    cvt_kernel<<<2048, 256, 0, stream>>>(gate, wg, N8);
    cvt_kernel<<<2048, 256, 0, stream>>>(up, wu, N8);

    gateup_kernel<<<MAX_TILES * (I_N / 128), 256, 0, stream>>>(
        x_buf, wg, wu, tile_expert, tile_row0, n_tiles, h_buf);

    cvt_kernel<<<2048, 256, 0, stream>>>(down, wd, N8);

    down_kernel<<<MAX_TILES * (H_N / 128), 256, 0, stream>>>(
        h_buf, wd, tile_expert, tile_row0, n_tiles, d_buf);

    combine_kernel<<<(T_N * H_N) / 256, 256, 0, stream>>>(d_buf, pair_slot,
                                                          rw, out);
}

// Round 3
// 512.952 us; speedup vs baseline: 1.0220x; 1.0220x over previous
//
#include <hip/hip_runtime.h>
#include <hip/hip_bf16.h>
#include <math.h>

// Problem constants (Qwen3 MoE experts)
#define E_N 32
#define H_N 1024
#define I_N 768
#define T_N 2048
#define K_N 8
#define MT  128                        // M-tile: slots per expert tile
#define NPAIRS (T_N * K_N)             // 16384 (t,k) pairs
#define MAX_SLOTS (NPAIRS + E_N * MT)  // 20480 padded slots (worst case)
#define MAX_TILES (NPAIRS / MT + E_N)  // 160 tiles (worst case)

typedef __attribute__((ext_vector_type(8))) short bf16x8;  // 8 bf16 = 4 VGPRs
typedef __attribute__((ext_vector_type(4))) short bf16x4;
typedef __attribute__((ext_vector_type(8))) float f32x8;
typedef __attribute__((ext_vector_type(4))) float f32x4;

// pack two fp32 -> two bf16 (round-half-up: ~0.5 ulp, 3 VALU)
__device__ __forceinline__ unsigned pk2(float a, float b) {
    unsigned ua = __float_as_uint(a) + 0x8000u;
    unsigned ub = __float_as_uint(b) + 0x8000u;
    return (ua >> 16) | (ub & 0xffff0000u);
}
__device__ __forceinline__ bf16x8 cvt8(f32x8 v) {
    union { unsigned u[4]; bf16x8 h; } r;
    r.u[0] = pk2(v[0], v[1]); r.u[1] = pk2(v[2], v[3]);
    r.u[2] = pk2(v[4], v[5]); r.u[3] = pk2(v[6], v[7]);
    return r.h;
}
__device__ __forceinline__ float bf2f(short s) {
    return __uint_as_float(((unsigned)(unsigned short)s) << 16);
}

// async global->LDS DMA, 16B per lane. LDS dest = wave-uniform base + lane*16
// (m104/m108). Global src is per-lane.
__device__ __forceinline__ void gload16(const void* g, void* l) {
    __builtin_amdgcn_global_load_lds(
        (const __attribute__((address_space(1))) unsigned int*)g,
        (__attribute__((address_space(3))) unsigned int*)l, 16, 0, 0);
}

// ---------------------------------------------------------------------------
// Routing, parallelized (old single-block route_kernel was a ~100 µs serial
// bottleneck: 2x16384 contended LDS atomics on ONE CU).
// 1a: 64-block LDS histogram -> global cnt (cnt_g pre-zeroed by memset)
// 1b: 1-block scan over 32 experts, build tile table + offsets
// 1c: 64-block placement via global atomics (slot order within expert is free)
// ---------------------------------------------------------------------------
__global__ __launch_bounds__(256) void hist_kernel(const int* __restrict__ sel,
                                                   int* __restrict__ cnt_g) {
    __shared__ int cnt[E_N];
    int tid = threadIdx.x;
    if (tid < E_N) cnt[tid] = 0;
    __syncthreads();
    int p = blockIdx.x * 256 + tid;      // grid 64 x 256 == NPAIRS
    atomicAdd(&cnt[sel[p]], 1);
    __syncthreads();
    if (tid < E_N) atomicAdd(&cnt_g[tid], cnt[tid]);
}

__global__ void scan_kernel(const int* __restrict__ cnt_g,
                            int* __restrict__ off_g,
                            int* __restrict__ tile_expert,
                            int* __restrict__ tile_row0,
                            int* __restrict__ n_tiles_out) {
    if (threadIdx.x == 0) {
        int acc = 0, tt = 0;
        for (int e = 0; e < E_N; ++e) {
            off_g[e] = acc;
            int nt = (cnt_g[e] + MT - 1) / MT;
            for (int i = 0; i < nt; ++i) {
                tile_expert[tt] = e;
                tile_row0[tt] = acc + i * MT;
                ++tt;
            }
            acc += nt * MT;
        }
        *n_tiles_out = tt;
    }
}

__global__ __launch_bounds__(256) void place_kernel(
    const int* __restrict__ sel,
    const int* __restrict__ off_g,
    int* __restrict__ cur_g,
    int* __restrict__ slot_token,
    int* __restrict__ pair_slot) {
    int p = blockIdx.x * 256 + threadIdx.x;  // grid 64 x 256 == NPAIRS
    int e = sel[p];
    int slot = off_g[e] + atomicAdd(&cur_g[e], 1);
    slot_token[slot] = p / K_N;
    pair_slot[p] = slot;
}

// ---------------------------------------------------------------------------
// Kernel 2: gather tokens -> contiguous bf16 x_buf[slot][H]; pad slots = 0.
// ---------------------------------------------------------------------------
__global__ __launch_bounds__(256) void gather_kernel(
    const float* __restrict__ hs,
    const int* __restrict__ slot_token,
    short* __restrict__ x_buf) {
    int idx = blockIdx.x * 256 + threadIdx.x;   // one thread per 4 elems
    int slot = idx >> 8;                        // H_N/4 = 256 threads/slot
    int pos = (idx & 255) * 4;
    int tok = slot_token[slot];
    union { unsigned u[2]; bf16x4 s; } o;
    if (tok >= 0) {
        f32x4 v = *(const f32x4*)(hs + (size_t)tok * H_N + pos);
        o.u[0] = pk2(v[0], v[1]);
        o.u[1] = pk2(v[2], v[3]);
    } else {
        o.u[0] = 0; o.u[1] = 0;
    }
    *(bf16x4*)(x_buf + (size_t)slot * H_N + pos) = o.s;
}

// ---------------------------------------------------------------------------
// Kernel 2b: weight convert fp32 -> bf16, grid-stride streaming.
// cvt2: two tensors in one launch (gate+up).
// ---------------------------------------------------------------------------
__global__ __launch_bounds__(256) void cvt2_kernel(
    const float* __restrict__ s0, short* __restrict__ d0,
    const float* __restrict__ s1, short* __restrict__ d1, int n8) {
    int i = blockIdx.x * 256 + threadIdx.x;
    int stride = gridDim.x * 256;
    for (; i < n8; i += stride) {
        f32x8 v0 = *(const f32x8*)(s0 + (size_t)i * 8);
        *(bf16x8*)(d0 + (size_t)i * 8) = cvt8(v0);
        f32x8 v1 = *(const f32x8*)(s1 + (size_t)i * 8);
        *(bf16x8*)(d1 + (size_t)i * 8) = cvt8(v1);
    }
}
__global__ __launch_bounds__(256) void cvt_kernel(
    const float* __restrict__ src, short* __restrict__ dst, int n8) {
    int i = blockIdx.x * 256 + threadIdx.x;
    int stride = gridDim.x * 256;
    for (; i < n8; i += stride) {
        f32x8 v = *(const f32x8*)(src + (size_t)i * 8);
        *(bf16x8*)(dst + (size_t)i * 8) = cvt8(v);
    }
}

// ---------------------------------------------------------------------------
// Kernel 3: gate/up GEMM + SwiGLU, m97 structure with BK=64:
// 128x128 tile, 4 waves (2x2), wave 64x64 for BOTH G and U (shared A).
// BK=64 held as TWO [128][32]-short LDS arrays per operand (proven
// conflict-free layout; no swizzle needed). One barrier pair per 64 K ->
// 32 MFMAs per vmcnt(0) drain (2x amortization vs BK=32).
// Staging: per array-half, 8 chunks of 16 rows x 64B; wave w stages chunks
// {2w,2w+1}; lane l covers row rb+(l>>2), 16B col-chunk (l&3).
// ---------------------------------------------------------------------------
__global__ __launch_bounds__(256, 2) void gateup_kernel(
    const short* __restrict__ x_buf,
    const short* __restrict__ wg,     // bf16 [E][I][H]
    const short* __restrict__ wu,     // bf16 [E][I][H]
    const int* __restrict__ tile_expert,
    const int* __restrict__ tile_row0,
    const int* __restrict__ n_tiles,
    __hip_bfloat16* __restrict__ h_buf) {
    // swizzle: 960 blocks, 120 consecutive work items per XCD
    int id = blockIdx.x;
    int W = (id & 7) * 120 + (id >> 3);
    int tile = W % MAX_TILES;       // tiles consecutive within an XCD's range
    int ycol = W / MAX_TILES;       // 0..5
    if (tile >= *n_tiles) return;
    __shared__ short sA[2][128 * 32];
    __shared__ short sG[2][128 * 32];
    __shared__ short sU[2][128 * 32];
    int e = tile_expert[tile];
    int row0 = tile_row0[tile];
    int col0 = ycol * 128;  // in I
    int tid = threadIdx.x;
    int wave = tid >> 6, lane = tid & 63, quad = lane >> 4, r16 = lane & 15;
    int m0w = (wave >> 1) * 64, n0w = (wave & 1) * 64;
    int srow = lane >> 2;         // 0..15 within staging chunk
    int scb = (lane & 3) * 8;     // 16B col-chunk (shorts)

    f32x4 accG[4][4], accU[4][4];
#pragma unroll
    for (int i = 0; i < 4; ++i)
#pragma unroll
        for (int j = 0; j < 4; ++j) {
            accG[i][j] = (f32x4){0.f, 0.f, 0.f, 0.f};
            accU[i][j] = (f32x4){0.f, 0.f, 0.f, 0.f};
        }

    const short* Ag = x_buf + (size_t)row0 * H_N;
    const short* Gg = wg + ((size_t)e * I_N + col0) * H_N;
    const short* Ug = wu + ((size_t)e * I_N + col0) * H_N;

#pragma unroll 1
    for (int k0 = 0; k0 < H_N; k0 += 64) {
        __syncthreads();  // prior iter's frag reads done before DMA overwrite
#pragma unroll
        for (int c = 0; c < 2; ++c) {
            int rb = (wave * 2 + c) * 16;          // chunk base row
            size_t goff = (size_t)(rb + srow) * H_N + k0 + scb;
            gload16(Ag + goff,      &sA[0][rb * 32]);
            gload16(Ag + goff + 32, &sA[1][rb * 32]);
            gload16(Gg + goff,      &sG[0][rb * 32]);
            gload16(Gg + goff + 32, &sG[1][rb * 32]);
            gload16(Ug + goff,      &sU[0][rb * 32]);
            gload16(Ug + goff + 32, &sU[1][rb * 32]);
        }
        __syncthreads();  // vmcnt(0)+lgkm drain: staged data visible
#pragma unroll
        for (int ks = 0; ks < 2; ++ks) {
            bf16x8 af[4], bg[4], bu[4];
#pragma unroll
            for (int mi = 0; mi < 4; ++mi)
                af[mi] = *(const bf16x8*)&sA[ks][(m0w + mi * 16 + r16) * 32 + quad * 8];
#pragma unroll
            for (int ni = 0; ni < 4; ++ni) {
                bg[ni] = *(const bf16x8*)&sG[ks][(n0w + ni * 16 + r16) * 32 + quad * 8];
                bu[ni] = *(const bf16x8*)&sU[ks][(n0w + ni * 16 + r16) * 32 + quad * 8];
            }
            __builtin_amdgcn_s_setprio(1);
#pragma unroll
            for (int mi = 0; mi < 4; ++mi)
#pragma unroll
                for (int ni = 0; ni < 4; ++ni) {
                    accG[mi][ni] = __builtin_amdgcn_mfma_f32_16x16x32_bf16(af[mi], bg[ni], accG[mi][ni], 0, 0, 0);
                    accU[mi][ni] = __builtin_amdgcn_mfma_f32_16x16x32_bf16(af[mi], bu[ni], accU[mi][ni], 0, 0, 0);
                }
            __builtin_amdgcn_s_setprio(0);
        }
    }
    // C/D layout: col(n)=lane&15, row(m)=quad*4+reg  [verified round 2]
#pragma unroll
    for (int mi = 0; mi < 4; ++mi)
#pragma unroll
        for (int ni = 0; ni < 4; ++ni)
#pragma unroll
            for (int r = 0; r < 4; ++r) {
                int m = m0w + mi * 16 + quad * 4 + r;
                int n = col0 + n0w + ni * 16 + r16;
                float g = accG[mi][ni][r], u = accU[mi][ni][r];
                float hval = g * u / (1.0f + __expf(-g));
                h_buf[(size_t)(row0 + m) * I_N + n] = __float2bfloat16(hval);
            }
}

// ---------------------------------------------------------------------------
// Kernel 4: down GEMM, same structure, BK=64. A = h_buf bf16, B = wd bf16
// [E][H][I]. 32KB LDS -> 3 blocks/CU.
// ---------------------------------------------------------------------------
__global__ __launch_bounds__(256, 3) void down_kernel(
    const __hip_bfloat16* __restrict__ h_buf,
    const short* __restrict__ wd,     // bf16 [E][H][I]
    const int* __restrict__ tile_expert,
    const int* __restrict__ tile_row0,
    const int* __restrict__ n_tiles,
    short* __restrict__ d_buf) {
    // swizzle: 1280 blocks, 160 consecutive work items per XCD
    int id = blockIdx.x;
    int W = (id & 7) * 160 + (id >> 3);
    int tile = W % MAX_TILES;
    int ycol = W / MAX_TILES;       // 0..7
    if (tile >= *n_tiles) return;
    __shared__ short sA[2][128 * 32];
    __shared__ short sB[2][128 * 32];
    int e = tile_expert[tile];
    int row0 = tile_row0[tile];
    int col0 = ycol * 128;  // in H
    int tid = threadIdx.x;
    int wave = tid >> 6, lane = tid & 63, quad = lane >> 4, r16 = lane & 15;
    int m0w = (wave >> 1) * 64, n0w = (wave & 1) * 64;
    int srow = lane >> 2;
    int scb = (lane & 3) * 8;

    f32x4 acc[4][4];
#pragma unroll
    for (int i = 0; i < 4; ++i)
#pragma unroll
        for (int j = 0; j < 4; ++j) acc[i][j] = (f32x4){0.f, 0.f, 0.f, 0.f};

    const short* Ag = (const short*)h_buf + (size_t)row0 * I_N;
    const short* Bg = wd + ((size_t)e * H_N + col0) * I_N;

#pragma unroll 1
    for (int k0 = 0; k0 < I_N; k0 += 64) {
        __syncthreads();
#pragma unroll
        for (int c = 0; c < 2; ++c) {
            int rb = (wave * 2 + c) * 16;
            size_t goff = (size_t)(rb + srow) * I_N + k0 + scb;
            gload16(Ag + goff,      &sA[0][rb * 32]);
            gload16(Ag + goff + 32, &sA[1][rb * 32]);
            gload16(Bg + goff,      &sB[0][rb * 32]);
            gload16(Bg + goff + 32, &sB[1][rb * 32]);
        }
        __syncthreads();
#pragma unroll
        for (int ks = 0; ks < 2; ++ks) {
            bf16x8 af[4], bf[4];
#pragma unroll
            for (int mi = 0; mi < 4; ++mi)
                af[mi] = *(const bf16x8*)&sA[ks][(m0w + mi * 16 + r16) * 32 + quad * 8];
#pragma unroll
            for (int ni = 0; ni < 4; ++ni)
                bf[ni] = *(const bf16x8*)&sB[ks][(n0w + ni * 16 + r16) * 32 + quad * 8];
            __builtin_amdgcn_s_setprio(1);
#pragma unroll
            for (int mi = 0; mi < 4; ++mi)
#pragma unroll
                for (int ni = 0; ni < 4; ++ni)
                    acc[mi][ni] = __builtin_amdgcn_mfma_f32_16x16x32_bf16(af[mi], bf[ni], acc[mi][ni], 0, 0, 0);
            __builtin_amdgcn_s_setprio(0);
        }
    }
#pragma unroll
    for (int mi = 0; mi < 4; ++mi)
#pragma unroll
        for (int ni = 0; ni < 4; ++ni)
#pragma unroll
            for (int r = 0; r < 4; ++r) {
                int m = m0w + mi * 16 + quad * 4 + r;
                int n = col0 + n0w + ni * 16 + r16;
                unsigned u = __float_as_uint(acc[mi][ni][r]) + 0x8000u;
                d_buf[(size_t)(row0 + m) * H_N + n] = (short)(u >> 16);
            }
}

// ---------------------------------------------------------------------------
// Kernel 5: combine. out[t,h] = sum_k rw[t,k] * d_buf[pair_slot[t,k], h].
// ---------------------------------------------------------------------------
__global__ __launch_bounds__(256) void combine_kernel(
    const short* __restrict__ d_buf,
    const int* __restrict__ pair_slot,
    const float* __restrict__ rw,
    float* __restrict__ out) {
    int idx = blockIdx.x * blockDim.x + threadIdx.x;
    int t = idx >> 10;          // H_N = 1024
    int h = idx & (H_N - 1);
    float acc = 0.f;
#pragma unroll
    for (int k = 0; k < K_N; ++k) {
        int slot = pair_slot[t * K_N + k];
        float w = rw[t * K_N + k];
        acc += w * bf2f(d_buf[(size_t)slot * H_N + h]);
    }
    out[idx] = acc;
}

// ---------------------------------------------------------------------------
extern "C" void kernel_launch(void* const* d_in, const int* in_sizes, int n_in,
                              void* d_out, int out_size, void* d_ws, size_t ws_size,
                              hipStream_t stream) {
    const float* hs   = (const float*)d_in[0];
    const float* rw   = (const float*)d_in[1];
    const int*   sel  = (const int*)d_in[2];
    const float* gate = (const float*)d_in[3];
    const float* up   = (const float*)d_in[4];
    const float* down = (const float*)d_in[5];
    float* out = (float*)d_out;

    // Workspace carve-up (256B-aligned), ~174 MB peak:
    //   misc tables | x_buf 41.9MB (reused as d_buf) | h_buf 31.5MB |
    //   w_buf 100.7MB (wg|wu during gateup; wd reuses wg's half for down)
    const size_t WN = (size_t)E_N * I_N * H_N;  // elems per weight tensor
    char* ws = (char*)d_ws;
    int* slot_token  = (int*)ws;  ws += ((size_t)MAX_SLOTS * 4 + 255) / 256 * 256;
    int* pair_slot   = (int*)ws;  ws += ((size_t)NPAIRS * 4 + 255) / 256 * 256;
    int* tile_expert = (int*)ws;  ws += ((size_t)MAX_TILES * 4 + 255) / 256 * 256;
    int* tile_row0   = (int*)ws;  ws += ((size_t)MAX_TILES * 4 + 255) / 256 * 256;
    int* n_tiles     = (int*)ws;  ws += 256;
    int* cnt_g       = (int*)ws;  ws += 256;   // 32 cnt
    int* cur_g       = (int*)ws;  ws += 256;   // 32 cur
    int* off_g       = (int*)ws;  ws += 256;   // 32 off
    short* x_buf = (short*)ws;    ws += ((size_t)MAX_SLOTS * H_N * 2 + 255) / 256 * 256;
    __hip_bfloat16* h_buf = (__hip_bfloat16*)ws;
    ws += ((size_t)MAX_SLOTS * I_N * 2 + 255) / 256 * 256;
    short* wg = (short*)ws;       // E*I*H bf16
    short* wu = wg + WN;          // E*I*H bf16
    short* wd = wg;               // reuses wg region after gateup
    short* d_buf = x_buf;         // reuses x region after gateup

    hipMemsetAsync(slot_token, 0xFF, (size_t)MAX_SLOTS * 4, stream);
    hipMemsetAsync(cnt_g, 0, 512, stream);  // cnt_g + cur_g

    hist_kernel<<<NPAIRS / 256, 256, 0, stream>>>(sel, cnt_g);
    scan_kernel<<<1, 64, 0, stream>>>(cnt_g, off_g, tile_expert, tile_row0, n_tiles);
    place_kernel<<<NPAIRS / 256, 256, 0, stream>>>(sel, off_g, cur_g,
                                                   slot_token, pair_slot);
    gather_kernel<<<(MAX_SLOTS * H_N / 4) / 256, 256, 0, stream>>>(hs, slot_token, x_buf);

    const int N8 = (int)(WN / 8);
    cvt2_kernel<<<2048, 256, 0, stream>>>(gate, wg, up, wu, N8);

    gateup_kernel<<<MAX_TILES * (I_N / 128), 256, 0, stream>>>(
        x_buf, wg, wu, tile_expert, tile_row0, n_tiles, h_buf);

    cvt_kernel<<<2048, 256, 0, stream>>>(down, wd, N8);

    down_kernel<<<MAX_TILES * (H_N / 128), 256, 0, stream>>>(
        h_buf, wd, tile_expert, tile_row0, n_tiles, d_buf);

    combine_kernel<<<(T_N * H_N) / 256, 256, 0, stream>>>(d_buf, pair_slot,
                                                          rw, out);
}

// Round 4
// 500.491 us; speedup vs baseline: 1.0475x; 1.0249x over previous
//
#include <hip/hip_runtime.h>
#include <hip/hip_bf16.h>
#include <math.h>

// Problem constants (Qwen3 MoE experts)
#define E_N 32
#define H_N 1024
#define I_N 768
#define T_N 2048
#define K_N 8
#define MT  128                        // M-tile: slots per expert tile
#define NPAIRS (T_N * K_N)             // 16384 (t,k) pairs
#define MAX_SLOTS (NPAIRS + E_N * MT)  // 20480 padded slots (worst case)
#define MAX_TILES (NPAIRS / MT + E_N)  // 160 tiles (worst case)

typedef __attribute__((ext_vector_type(8))) short bf16x8;  // 8 bf16 = 4 VGPRs
typedef __attribute__((ext_vector_type(4))) short bf16x4;
typedef __attribute__((ext_vector_type(8))) float f32x8;
typedef __attribute__((ext_vector_type(4))) float f32x4;

// pack two fp32 -> two bf16 (round-half-up: ~0.5 ulp, 3 VALU)
__device__ __forceinline__ unsigned pk2(float a, float b) {
    unsigned ua = __float_as_uint(a) + 0x8000u;
    unsigned ub = __float_as_uint(b) + 0x8000u;
    return (ua >> 16) | (ub & 0xffff0000u);
}
__device__ __forceinline__ bf16x8 cvt8(f32x8 v) {
    union { unsigned u[4]; bf16x8 h; } r;
    r.u[0] = pk2(v[0], v[1]); r.u[1] = pk2(v[2], v[3]);
    r.u[2] = pk2(v[4], v[5]); r.u[3] = pk2(v[6], v[7]);
    return r.h;
}
__device__ __forceinline__ float bf2f(short s) {
    return __uint_as_float(((unsigned)(unsigned short)s) << 16);
}

// async global->LDS DMA, 16B per lane. LDS dest = wave-uniform base + lane*16
// (linear fill, m104/m108). Global src is per-lane -> source pre-swizzle OK.
__device__ __forceinline__ void gload16(const void* g, void* l) {
    __builtin_amdgcn_global_load_lds(
        (const __attribute__((address_space(1))) unsigned int*)g,
        (__attribute__((address_space(3))) unsigned int*)l, 16, 0, 0);
}

// ---------------------------------------------------------------------------
// Routing (parallel, 3 tiny kernels).
// ---------------------------------------------------------------------------
__global__ __launch_bounds__(256) void hist_kernel(const int* __restrict__ sel,
                                                   int* __restrict__ cnt_g) {
    __shared__ int cnt[E_N];
    int tid = threadIdx.x;
    if (tid < E_N) cnt[tid] = 0;
    __syncthreads();
    int p = blockIdx.x * 256 + tid;      // grid 64 x 256 == NPAIRS
    atomicAdd(&cnt[sel[p]], 1);
    __syncthreads();
    if (tid < E_N) atomicAdd(&cnt_g[tid], cnt[tid]);
}

__global__ void scan_kernel(const int* __restrict__ cnt_g,
                            int* __restrict__ off_g,
                            int* __restrict__ tile_expert,
                            int* __restrict__ tile_row0,
                            int* __restrict__ n_tiles_out) {
    if (threadIdx.x == 0) {
        int acc = 0, tt = 0;
        for (int e = 0; e < E_N; ++e) {
            off_g[e] = acc;
            int nt = (cnt_g[e] + MT - 1) / MT;
            for (int i = 0; i < nt; ++i) {
                tile_expert[tt] = e;
                tile_row0[tt] = acc + i * MT;
                ++tt;
            }
            acc += nt * MT;
        }
        *n_tiles_out = tt;
    }
}

__global__ __launch_bounds__(256) void place_kernel(
    const int* __restrict__ sel,
    const int* __restrict__ off_g,
    int* __restrict__ cur_g,
    int* __restrict__ slot_token,
    int* __restrict__ pair_slot) {
    int p = blockIdx.x * 256 + threadIdx.x;  // grid 64 x 256 == NPAIRS
    int e = sel[p];
    int slot = off_g[e] + atomicAdd(&cur_g[e], 1);
    slot_token[slot] = p / K_N;
    pair_slot[p] = slot;
}

// ---------------------------------------------------------------------------
// Kernel 2: gather tokens -> contiguous bf16 x_buf[slot][H]; pad slots = 0.
// ---------------------------------------------------------------------------
__global__ __launch_bounds__(256) void gather_kernel(
    const float* __restrict__ hs,
    const int* __restrict__ slot_token,
    short* __restrict__ x_buf) {
    int idx = blockIdx.x * 256 + threadIdx.x;   // one thread per 4 elems
    int slot = idx >> 8;                        // H_N/4 = 256 threads/slot
    int pos = (idx & 255) * 4;
    int tok = slot_token[slot];
    union { unsigned u[2]; bf16x4 s; } o;
    if (tok >= 0) {
        f32x4 v = *(const f32x4*)(hs + (size_t)tok * H_N + pos);
        o.u[0] = pk2(v[0], v[1]);
        o.u[1] = pk2(v[2], v[3]);
    } else {
        o.u[0] = 0; o.u[1] = 0;
    }
    *(bf16x4*)(x_buf + (size_t)slot * H_N + pos) = o.s;
}

// ---------------------------------------------------------------------------
// Kernel 3: gate/up GEMM + SwiGLU with FUSED fp32->bf16 weight conversion.
// 128x128 tile, 4 waves (2x2), wave 64x64 for BOTH G and U (shared A), BK=32.
// - A (bf16 x_buf): global_load_lds DMA, DOUBLE-buffered; DMA for k+1 issued
//   in the compute phase so its latency hides under MFMA (drained at next
//   sync1 after ~a full compute phase in flight).
// - G/U (fp32 weights): reg-prefetch one iter ahead (issued after sync2,
//   fly under MFMA), cvt8 + ds_write between sync1/sync2. No cvt pass, no
//   bf16 weight round-trip through HBM.
// - LDS chunk swizzle: 16B chunk index XOR (row&3). A: applied on the DMA
//   global SOURCE (LDS stays linear, m173). G/U: applied on ds_write addr.
//   Frag reads use chunk = quad ^ (r16&3). Spreads the 16-lane 64B-stride
//   read over all 32 banks (was ~8-way -> 5.27M conflict cycles).
// ---------------------------------------------------------------------------
__global__ __launch_bounds__(256, 2) void gateup_kernel(
    const short* __restrict__ x_buf,
    const float* __restrict__ gate,   // fp32 [E][I][H]
    const float* __restrict__ up,     // fp32 [E][I][H]
    const int* __restrict__ tile_expert,
    const int* __restrict__ tile_row0,
    const int* __restrict__ n_tiles,
    __hip_bfloat16* __restrict__ h_buf) {
    // swizzle: 960 blocks, 120 consecutive work items per XCD
    int id = blockIdx.x;
    int W = (id & 7) * 120 + (id >> 3);
    int tile = W % MAX_TILES;       // tiles consecutive within an XCD's range
    int ycol = W / MAX_TILES;       // 0..5
    if (tile >= *n_tiles) return;
    __shared__ short sA[2][128 * 32];
    __shared__ short sG[128 * 32];
    __shared__ short sU[128 * 32];
    int e = tile_expert[tile];
    int row0 = tile_row0[tile];
    int col0 = ycol * 128;  // in I
    int tid = threadIdx.x;
    int wave = tid >> 6, lane = tid & 63, quad = lane >> 4, r16 = lane & 15;
    int m0w = (wave >> 1) * 64, n0w = (wave & 1) * 64;
    // DMA staging: wave stages 2 chunks of 16 rows; lane covers row lane>>2,
    // 16B col-chunk (lane&3) -> source col pre-swizzled by row&3.
    int srow_d = lane >> 2;
    int scb_sw = (((lane & 3) ^ (srow_d & 3)) * 8);
    // reg staging (weights): thread covers rows {tid>>2, 64+(tid>>2)},
    // fp32 col chunk tid&3 (32B); LDS write chunk swizzled.
    int srow_r = tid >> 2;
    int scol = (tid & 3) * 8;
    int wchk = ((tid & 3) ^ (srow_r & 3)) * 8;
    int qsw = (quad ^ (r16 & 3)) * 8;   // frag-read chunk (shorts)

    f32x4 accG[4][4], accU[4][4];
#pragma unroll
    for (int i = 0; i < 4; ++i)
#pragma unroll
        for (int j = 0; j < 4; ++j) {
            accG[i][j] = (f32x4){0.f, 0.f, 0.f, 0.f};
            accU[i][j] = (f32x4){0.f, 0.f, 0.f, 0.f};
        }

    const short* Ag = x_buf + (size_t)row0 * H_N;
    const float* Gg = gate + ((size_t)e * I_N + col0) * H_N;
    const float* Ug = up + ((size_t)e * I_N + col0) * H_N;

    f32x8 pg[2], pu[2];
    // prologue: weights(k0=0) -> regs; A(k0=0) -> sA[0] via DMA
#pragma unroll
    for (int r = 0; r < 2; ++r) {
        int row = r * 64 + srow_r;
        pg[r] = *(const f32x8*)(Gg + (size_t)row * H_N + scol);
        pu[r] = *(const f32x8*)(Ug + (size_t)row * H_N + scol);
    }
#pragma unroll
    for (int c = 0; c < 2; ++c) {
        int rb = (wave * 2 + c) * 16;
        gload16(Ag + (size_t)(rb + srow_d) * H_N + scb_sw, &sA[0][rb * 32]);
    }

    int cur = 0;
#pragma unroll 1
    for (int k0 = 0; k0 < H_N; k0 += 32) {
        __syncthreads();  // drains pg/pu(k0) + A-DMA(k0) (in flight 1 phase)
        // commit weights k0 into LDS (cvt in regs)
#pragma unroll
        for (int r = 0; r < 2; ++r) {
            int row = r * 64 + srow_r;
            *(bf16x8*)&sG[row * 32 + wchk] = cvt8(pg[r]);
            *(bf16x8*)&sU[row * 32 + wchk] = cvt8(pu[r]);
        }
        __syncthreads();  // sG/sU + sA[cur] visible
        if (k0 + 32 < H_N) {
            int kn = k0 + 32;
            // weight prefetch k+1: flies under MFMA + next staging phase
#pragma unroll
            for (int r = 0; r < 2; ++r) {
                int row = r * 64 + srow_r;
                pg[r] = *(const f32x8*)(Gg + (size_t)row * H_N + kn + scol);
                pu[r] = *(const f32x8*)(Ug + (size_t)row * H_N + kn + scol);
            }
            // A DMA k+1 into other buffer: flies under MFMA
#pragma unroll
            for (int c = 0; c < 2; ++c) {
                int rb = (wave * 2 + c) * 16;
                gload16(Ag + (size_t)(rb + srow_d) * H_N + kn + scb_sw,
                        &sA[cur ^ 1][rb * 32]);
            }
        }
        bf16x8 af[4], bg[4], bu[4];
#pragma unroll
        for (int mi = 0; mi < 4; ++mi)
            af[mi] = *(const bf16x8*)&sA[cur][(m0w + mi * 16 + r16) * 32 + qsw];
#pragma unroll
        for (int ni = 0; ni < 4; ++ni) {
            bg[ni] = *(const bf16x8*)&sG[(n0w + ni * 16 + r16) * 32 + qsw];
            bu[ni] = *(const bf16x8*)&sU[(n0w + ni * 16 + r16) * 32 + qsw];
        }
        __builtin_amdgcn_s_setprio(1);
#pragma unroll
        for (int mi = 0; mi < 4; ++mi)
#pragma unroll
            for (int ni = 0; ni < 4; ++ni) {
                accG[mi][ni] = __builtin_amdgcn_mfma_f32_16x16x32_bf16(af[mi], bg[ni], accG[mi][ni], 0, 0, 0);
                accU[mi][ni] = __builtin_amdgcn_mfma_f32_16x16x32_bf16(af[mi], bu[ni], accU[mi][ni], 0, 0, 0);
            }
        __builtin_amdgcn_s_setprio(0);
        cur ^= 1;
    }
    // C/D layout: col(n)=lane&15, row(m)=quad*4+reg  [verified round 2]
#pragma unroll
    for (int mi = 0; mi < 4; ++mi)
#pragma unroll
        for (int ni = 0; ni < 4; ++ni)
#pragma unroll
            for (int r = 0; r < 4; ++r) {
                int m = m0w + mi * 16 + quad * 4 + r;
                int n = col0 + n0w + ni * 16 + r16;
                float g = accG[mi][ni][r], u = accU[mi][ni][r];
                float hval = g * u / (1.0f + __expf(-g));
                h_buf[(size_t)(row0 + m) * I_N + n] = __float2bfloat16(hval);
            }
}

// ---------------------------------------------------------------------------
// Kernel 4: down GEMM with fused cvt, same structure. A = h_buf bf16 (DMA,
// dbuf); B = down fp32 (reg-staged + cvt). 24KB LDS -> 3 blocks/CU.
// ---------------------------------------------------------------------------
__global__ __launch_bounds__(256, 3) void down_kernel(
    const __hip_bfloat16* __restrict__ h_buf,
    const float* __restrict__ down,   // fp32 [E][H][I]
    const int* __restrict__ tile_expert,
    const int* __restrict__ tile_row0,
    const int* __restrict__ n_tiles,
    short* __restrict__ d_buf) {
    // swizzle: 1280 blocks, 160 consecutive work items per XCD
    int id = blockIdx.x;
    int W = (id & 7) * 160 + (id >> 3);
    int tile = W % MAX_TILES;
    int ycol = W / MAX_TILES;       // 0..7
    if (tile >= *n_tiles) return;
    __shared__ short sA[2][128 * 32];
    __shared__ short sB[128 * 32];
    int e = tile_expert[tile];
    int row0 = tile_row0[tile];
    int col0 = ycol * 128;  // in H
    int tid = threadIdx.x;
    int wave = tid >> 6, lane = tid & 63, quad = lane >> 4, r16 = lane & 15;
    int m0w = (wave >> 1) * 64, n0w = (wave & 1) * 64;
    int srow_d = lane >> 2;
    int scb_sw = (((lane & 3) ^ (srow_d & 3)) * 8);
    int srow_r = tid >> 2;
    int scol = (tid & 3) * 8;
    int wchk = ((tid & 3) ^ (srow_r & 3)) * 8;
    int qsw = (quad ^ (r16 & 3)) * 8;

    f32x4 acc[4][4];
#pragma unroll
    for (int i = 0; i < 4; ++i)
#pragma unroll
        for (int j = 0; j < 4; ++j) acc[i][j] = (f32x4){0.f, 0.f, 0.f, 0.f};

    const short* Ag = (const short*)h_buf + (size_t)row0 * I_N;
    const float* Bg = down + ((size_t)e * H_N + col0) * I_N;

    f32x8 pb[2];
#pragma unroll
    for (int r = 0; r < 2; ++r) {
        int row = r * 64 + srow_r;
        pb[r] = *(const f32x8*)(Bg + (size_t)row * I_N + scol);
    }
#pragma unroll
    for (int c = 0; c < 2; ++c) {
        int rb = (wave * 2 + c) * 16;
        gload16(Ag + (size_t)(rb + srow_d) * I_N + scb_sw, &sA[0][rb * 32]);
    }

    int cur = 0;
#pragma unroll 1
    for (int k0 = 0; k0 < I_N; k0 += 32) {
        __syncthreads();
#pragma unroll
        for (int r = 0; r < 2; ++r) {
            int row = r * 64 + srow_r;
            *(bf16x8*)&sB[row * 32 + wchk] = cvt8(pb[r]);
        }
        __syncthreads();
        if (k0 + 32 < I_N) {
            int kn = k0 + 32;
#pragma unroll
            for (int r = 0; r < 2; ++r) {
                int row = r * 64 + srow_r;
                pb[r] = *(const f32x8*)(Bg + (size_t)row * I_N + kn + scol);
            }
#pragma unroll
            for (int c = 0; c < 2; ++c) {
                int rb = (wave * 2 + c) * 16;
                gload16(Ag + (size_t)(rb + srow_d) * I_N + kn + scb_sw,
                        &sA[cur ^ 1][rb * 32]);
            }
        }
        bf16x8 af[4], bf[4];
#pragma unroll
        for (int mi = 0; mi < 4; ++mi)
            af[mi] = *(const bf16x8*)&sA[cur][(m0w + mi * 16 + r16) * 32 + qsw];
#pragma unroll
        for (int ni = 0; ni < 4; ++ni)
            bf[ni] = *(const bf16x8*)&sB[(n0w + ni * 16 + r16) * 32 + qsw];
        __builtin_amdgcn_s_setprio(1);
#pragma unroll
        for (int mi = 0; mi < 4; ++mi)
#pragma unroll
            for (int ni = 0; ni < 4; ++ni)
                acc[mi][ni] = __builtin_amdgcn_mfma_f32_16x16x32_bf16(af[mi], bf[ni], acc[mi][ni], 0, 0, 0);
        __builtin_amdgcn_s_setprio(0);
        cur ^= 1;
    }
#pragma unroll
    for (int mi = 0; mi < 4; ++mi)
#pragma unroll
        for (int ni = 0; ni < 4; ++ni)
#pragma unroll
            for (int r = 0; r < 4; ++r) {
                int m = m0w + mi * 16 + quad * 4 + r;
                int n = col0 + n0w + ni * 16 + r16;
                unsigned u = __float_as_uint(acc[mi][ni][r]) + 0x8000u;
                d_buf[(size_t)(row0 + m) * H_N + n] = (short)(u >> 16);
            }
}

// ---------------------------------------------------------------------------
// Kernel 5: combine. out[t,h] = sum_k rw[t,k] * d_buf[pair_slot[t,k], h].
// ---------------------------------------------------------------------------
__global__ __launch_bounds__(256) void combine_kernel(
    const short* __restrict__ d_buf,
    const int* __restrict__ pair_slot,
    const float* __restrict__ rw,
    float* __restrict__ out) {
    int idx = blockIdx.x * blockDim.x + threadIdx.x;
    int t = idx >> 10;          // H_N = 1024
    int h = idx & (H_N - 1);
    float acc = 0.f;
#pragma unroll
    for (int k = 0; k < K_N; ++k) {
        int slot = pair_slot[t * K_N + k];
        float w = rw[t * K_N + k];
        acc += w * bf2f(d_buf[(size_t)slot * H_N + h]);
    }
    out[idx] = acc;
}

// ---------------------------------------------------------------------------
extern "C" void kernel_launch(void* const* d_in, const int* in_sizes, int n_in,
                              void* d_out, int out_size, void* d_ws, size_t ws_size,
                              hipStream_t stream) {
    const float* hs   = (const float*)d_in[0];
    const float* rw   = (const float*)d_in[1];
    const int*   sel  = (const int*)d_in[2];
    const float* gate = (const float*)d_in[3];
    const float* up   = (const float*)d_in[4];
    const float* down = (const float*)d_in[5];
    float* out = (float*)d_out;

    // Workspace carve-up (256B-aligned), ~74 MB:
    //   misc tables | x_buf 41.9MB (reused as d_buf) | h_buf 31.5MB
    char* ws = (char*)d_ws;
    int* slot_token  = (int*)ws;  ws += ((size_t)MAX_SLOTS * 4 + 255) / 256 * 256;
    int* pair_slot   = (int*)ws;  ws += ((size_t)NPAIRS * 4 + 255) / 256 * 256;
    int* tile_expert = (int*)ws;  ws += ((size_t)MAX_TILES * 4 + 255) / 256 * 256;
    int* tile_row0   = (int*)ws;  ws += ((size_t)MAX_TILES * 4 + 255) / 256 * 256;
    int* n_tiles     = (int*)ws;  ws += 256;
    int* cnt_g       = (int*)ws;  ws += 256;   // 32 cnt
    int* cur_g       = (int*)ws;  ws += 256;   // 32 cur
    int* off_g       = (int*)ws;  ws += 256;   // 32 off
    short* x_buf = (short*)ws;    ws += ((size_t)MAX_SLOTS * H_N * 2 + 255) / 256 * 256;
    __hip_bfloat16* h_buf = (__hip_bfloat16*)ws;
    short* d_buf = x_buf;         // reuses x region after gateup

    hipMemsetAsync(slot_token, 0xFF, (size_t)MAX_SLOTS * 4, stream);
    hipMemsetAsync(cnt_g, 0, 512, stream);  // cnt_g + cur_g

    hist_kernel<<<NPAIRS / 256, 256, 0, stream>>>(sel, cnt_g);
    scan_kernel<<<1, 64, 0, stream>>>(cnt_g, off_g, tile_expert, tile_row0, n_tiles);
    place_kernel<<<NPAIRS / 256, 256, 0, stream>>>(sel, off_g, cur_g,
                                                   slot_token, pair_slot);
    gather_kernel<<<(MAX_SLOTS * H_N / 4) / 256, 256, 0, stream>>>(hs, slot_token, x_buf);

    gateup_kernel<<<MAX_TILES * (I_N / 128), 256, 0, stream>>>(
        x_buf, gate, up, tile_expert, tile_row0, n_tiles, h_buf);

    down_kernel<<<MAX_TILES * (H_N / 128), 256, 0, stream>>>(
        h_buf, down, tile_expert, tile_row0, n_tiles, d_buf);

    combine_kernel<<<(T_N * H_N) / 256, 256, 0, stream>>>(d_buf, pair_slot,
                                                          rw, out);
}